// Round 5
// baseline (369.517 us; speedup 1.0000x reference)
//
#include <hip/hip_runtime.h>

// B=8, T=20, C=1, H=512, W=512
#define FRAMES 160
#define HH 512
#define WW 512
#define WSTRIPS 16               // wave-strips per frame (32 rows each, last 26)
#define NW (WSTRIPS * FRAMES)    // 2560 partial slots
#define NTOT 41943040

// SSIM on raw [0,1) values (scale-invariance folds *255 into C1,C2),
// everything premultiplied by NP^2 (NP=49). szz = sxx + syy (SSIM never
// needs sxx and syy separately: B2 = vx+vy+C2).
__device__ __forceinline__ float ssim_fast(float a, float b, float szz,
                                           float sxy) {
  const float K1 = 0.2401f;       // 2401 * 1e-4
  const float K2 = 2.1609f;       // 2401 * 9e-4
  const float cA = 49.0f / 24.0f;
  const float cB = 49.0f / 48.0f;
  float ab = a * b;
  float s2 = fmaf(a, a, b * b);
  float A1 = fmaf(2.0f, ab, K1);
  float B1 = s2 + K1;
  float A2 = fmaf(cA, fmaf(49.0f, sxy, -ab), K2);
  float B2 = fmaf(cB, fmaf(49.0f, szz, -s2), K2);
  return (A1 * A2) * __builtin_amdgcn_rcpf(B1 * B2);
}

#define LOAD8(dst, ptr) {                         \
  float4 lo_ = *(const float4*)(ptr);             \
  float4 hi_ = *(const float4*)((ptr) + 4);       \
  dst[0] = lo_.x; dst[1] = lo_.y;                 \
  dst[2] = lo_.z; dst[3] = lo_.w;                 \
  dst[4] = hi_.x; dst[5] = hi_.y;                 \
  dst[6] = hi_.z; dst[7] = hi_.w; }

// One wave per (frame, strip). Lane owns cols 8*lane..8*lane+7 (64*8=512).
// Strip s: output rows [32s, 32s+R), R=32 (s<15) / 26 (s=15); owns input
// rows [32s, 32s+32) for L_rec: init rows (6) + new rows with r<=25 (26).
// Horizontal exchange: per array, lane needs next lane's prefix P0..P5 ->
// 6 shfl_down; zero LDS, zero barriers in the hot loop.
// Grid (FRAMES, WSTRIPS): strip partners (same frame, strip+-1) are 160
// blocks apart = 0 mod 8 -> same XCD -> 6-row overlap reads hit that L2.
__global__ __launch_bounds__(64) void fused_kernel(
    const float* __restrict__ gsrc, const float* __restrict__ tsrc,
    float* __restrict__ ws) {
  const int frame = blockIdx.x;
  const int strip = blockIdx.y;
  const int row0 = strip * 32;
  const int R = (strip == WSTRIPS - 1) ? 26 : 32;
  const int lane = threadIdx.x;

  const float* gp = gsrc + ((size_t)frame * HH + row0) * WW + lane * 8;
  const float* tp = tsrc + ((size_t)frame * HH + row0) * WW + lane * 8;

  float sx[8], sy[8], szz[8], sxy[8];
  #pragma unroll
  for (int k = 0; k < 8; ++k) {
    sx[k] = 0.f; sy[k] = 0.f; szz[k] = 0.f; sxy[k] = 0.f;
  }
  float sabs = 0.f, ssq = 0.f, ssum = 0.f;

  // init: rows 0..5 (all owned -> L_rec)
  #pragma unroll
  for (int i = 0; i < 6; ++i) {
    float xv[8], yv[8];
    LOAD8(xv, gp + i * WW)
    LOAD8(yv, tp + i * WW)
    #pragma unroll
    for (int k = 0; k < 8; ++k) {
      sx[k] += xv[k];
      sy[k] += yv[k];
      szz[k] = fmaf(xv[k], xv[k], szz[k]);
      szz[k] = fmaf(yv[k], yv[k], szz[k]);
      sxy[k] = fmaf(xv[k], yv[k], sxy[k]);
      float d = xv[k] - yv[k];
      sabs += fabsf(d);
      ssq = fmaf(d, d, ssq);
    }
  }

  for (int r = 0; r < R; ++r) {
    // new row r+6; retire row r (re-read from global: exact same values as
    // when added -> exact cancellation; tiny reuse distance -> L2-served).
    float nx[8], ny[8];
    LOAD8(nx, gp + (r + 6) * WW)
    LOAD8(ny, tp + (r + 6) * WW)
    const bool ret = (r + 1 < R);
    float ox[8], oy[8];
    if (ret) {
      LOAD8(ox, gp + r * WW)
      LOAD8(oy, tp + r * WW)
    }

    #pragma unroll
    for (int k = 0; k < 8; ++k) {
      sx[k] += nx[k];
      sy[k] += ny[k];
      szz[k] = fmaf(nx[k], nx[k], szz[k]);
      szz[k] = fmaf(ny[k], ny[k], szz[k]);
      sxy[k] = fmaf(nx[k], ny[k], sxy[k]);
    }
    if (r <= 25) {  // owned new row -> L_rec (uniform branch)
      #pragma unroll
      for (int k = 0; k < 8; ++k) {
        float d = nx[k] - ny[k];
        sabs += fabsf(d);
        ssq = fmaf(d, d, ssq);
      }
    }

    // per-lane inclusive prefix over the 8 column sums, 4 arrays
    float px[8], py[8], pz[8], pq[8];
    px[0] = sx[0]; py[0] = sy[0]; pz[0] = szz[0]; pq[0] = sxy[0];
    #pragma unroll
    for (int k = 1; k < 8; ++k) {
      px[k] = px[k - 1] + sx[k];
      py[k] = py[k - 1] + sy[k];
      pz[k] = pz[k - 1] + szz[k];
      pq[k] = pq[k - 1] + sxy[k];
    }
    // next lane's P0..P5 (lane 63 gets garbage; its j>=2 are discarded)
    float nxp[6], nyp[6], nzp[6], nqp[6];
    #pragma unroll
    for (int k = 0; k < 6; ++k) {
      nxp[k] = __shfl_down(px[k], 1, 64);
      nyp[k] = __shfl_down(py[k], 1, 64);
      nzp[k] = __shfl_down(pz[k], 1, 64);
      nqp[k] = __shfl_down(pq[k], 1, 64);
    }

    // j=0: cols 8L..8L+6 (valid for all lanes: 8*63=504 <= 505)
    ssum += ssim_fast(px[6], py[6], pz[6], pq[6]);
    // j=1: cols 8L+1..8L+7 (8*63+1=505 <= 505)
    ssum += ssim_fast(px[7] - px[0], py[7] - py[0], pz[7] - pz[0],
                      pq[7] - pq[0]);
    // j=2..7: need neighbor; invalid for lane 63 (col >= 506).
    #pragma unroll
    for (int j = 2; j < 8; ++j) {
      float wx = (px[7] - px[j - 1]) + nxp[j - 2];
      float wy = (py[7] - py[j - 1]) + nyp[j - 2];
      float wz = (pz[7] - pz[j - 1]) + nzp[j - 2];
      float wq = (pq[7] - pq[j - 1]) + nqp[j - 2];
      float v = ssim_fast(wx, wy, wz, wq);
      ssum += (lane < 63) ? v : 0.f;  // select-then-add: NaN-safe
    }

    if (ret) {
      #pragma unroll
      for (int k = 0; k < 8; ++k) {
        sx[k] -= ox[k];
        sy[k] -= oy[k];
        szz[k] = fmaf(-ox[k], ox[k], szz[k]);
        szz[k] = fmaf(-oy[k], oy[k], szz[k]);
        sxy[k] = fmaf(-ox[k], oy[k], sxy[k]);
      }
    }
  }

  // wave-level reduce; lane 0 writes the partials (no LDS, single wave)
  #pragma unroll
  for (int off = 32; off > 0; off >>= 1) {
    sabs += __shfl_down(sabs, off, 64);
    ssq += __shfl_down(ssq, off, 64);
    ssum += __shfl_down(ssum, off, 64);
  }
  if (lane == 0) {
    const int wid = strip * FRAMES + frame;
    ws[wid] = sabs;
    ws[NW + wid] = ssq;
    ws[2 * NW + wid] = ssum;
  }
}

__global__ __launch_bounds__(256) void finalize_kernel(
    const float* __restrict__ ws, const float* __restrict__ genD,
    float* __restrict__ out) {
  const int tid = threadIdx.x;
  float a = 0.f, b = 0.f, c = 0.f;
  for (int i = tid; i < NW; i += 256) {
    a += ws[i];
    b += ws[NW + i];
    c += ws[2 * NW + i];
  }
  #pragma unroll
  for (int off = 32; off > 0; off >>= 1) {
    a += __shfl_down(a, off, 64);
    b += __shfl_down(b, off, 64);
    c += __shfl_down(c, off, 64);
  }
  __shared__ float la[4], lb[4], lc[4];
  const int lane = tid & 63, wv = tid >> 6;
  if (lane == 0) { la[wv] = a; lb[wv] = b; lc[wv] = c; }
  __syncthreads();
  if (tid == 0) {
    a = la[0] + la[1] + la[2] + la[3];
    b = lb[0] + lb[1] + lb[2] + lb[3];
    c = lc[0] + lc[1] + lc[2] + lc[3];
    const float invN = 1.0f / (float)NTOT;
    float L_rec = a * invN + b * invN;
    float L_ssim = c / (160.0f * 506.0f * 506.0f);
    float d = 0.f;
    #pragma unroll
    for (int i = 0; i < 8; ++i) d += genD[i];
    float L_adv = -d / 8.0f;
    float L_total = L_rec + 0.01f * (1.0f - L_ssim) + 0.0001f * L_adv;
    out[0] = L_total;
    out[1] = L_rec;
    out[2] = L_ssim;
    out[3] = L_adv;
  }
}

extern "C" void kernel_launch(void* const* d_in, const int* in_sizes, int n_in,
                              void* d_out, int out_size, void* d_ws,
                              size_t ws_size, hipStream_t stream) {
  const float* gen_img = (const float*)d_in[0];
  const float* target = (const float*)d_in[1];
  const float* gen_D = (const float*)d_in[2];
  float* out = (float*)d_out;
  float* ws = (float*)d_ws;

  dim3 grid(FRAMES, WSTRIPS);
  fused_kernel<<<grid, 64, 0, stream>>>(gen_img, target, ws);
  finalize_kernel<<<1, 256, 0, stream>>>(ws, gen_D, out);
}